// Round 1
// baseline (530.623 us; speedup 1.0000x reference)
//
#include <hip/hip_runtime.h>
#include <hip/hip_bf16.h>

typedef __attribute__((ext_vector_type(8))) short short8;
typedef __attribute__((ext_vector_type(4))) short short4v;
typedef __attribute__((ext_vector_type(4))) float f32x4;

#define DEVI static __device__ __forceinline__

#define MTOK 8192
#define CDIM 1024
#define HN 16
#define HD 64
#define TSEQ 2048

DEVI short bf16_rne(float f) {
  union { float f; unsigned u; } v; v.f = f;
  unsigned r = v.u + 0x7FFFu + ((v.u >> 16) & 1u);
  return (short)(r >> 16);
}

DEVI void gload16(const void* g, void* l) {
  __builtin_amdgcn_global_load_lds(
      (const __attribute__((address_space(1))) void*)(unsigned long long)g,
      (__attribute__((address_space(3))) void*)(unsigned long long)l, 16, 0, 0);
}

#define MFMA_B16(A,B,C) __builtin_amdgcn_mfma_f32_16x16x32_bf16(A,B,C,0,0,0)

// ---------------- pack: fp32 -> bf16 for x, W_attn, W_proj ----------------
__global__ void pack_kernel(const float* __restrict__ x, const float* __restrict__ Wa,
                            const float* __restrict__ Wp,
                            short* __restrict__ xb, short* __restrict__ wab,
                            short* __restrict__ wpb) {
  const int NX4 = MTOK*CDIM/4, NA4 = 3*CDIM*CDIM/4, NP4 = CDIM*CDIM/4;
  const int total = NX4 + NA4 + NP4;
  for (int i = blockIdx.x*blockDim.x + threadIdx.x; i < total; i += gridDim.x*blockDim.x) {
    const float* src; short* dst; int off;
    if (i < NX4)          { src = x;  dst = xb;  off = i*4; }
    else if (i < NX4+NA4) { src = Wa; dst = wab; off = (i-NX4)*4; }
    else                  { src = Wp; dst = wpb; off = (i-NX4-NA4)*4; }
    float4 v = *(const float4*)(src + off);
    short4v r;
    r.x = bf16_rne(v.x); r.y = bf16_rne(v.y); r.z = bf16_rne(v.z); r.w = bf16_rne(v.w);
    *(short4v*)(dst + off) = r;
  }
}

// ---------------- T5 relative-position bias table: tab[h][dist] ----------------
__global__ void bias_table_kernel(const float* __restrict__ rel_emb, float* __restrict__ tab) {
  int d = blockIdx.x*blockDim.x + threadIdx.x;
  if (d >= TSEQ) return;
  int bucket;
  if (d < 16) bucket = d;
  else {
    // match jnp: 16 + int32(log(d/16 + 1e-10)/log(8) * 16), clipped to 31
    int bl = 16 + (int)(logf((float)d / 16.0f + 1e-10f) / 2.0794415416798357f * 16.0f);
    bucket = bl < 31 ? bl : 31;
  }
  for (int h = 0; h < HN; h++) tab[h*TSEQ + d] = rel_emb[bucket*HN + h];
}

// ---------------- GEMM C = A @ B^T (+bias), A[M][1024], B[N][1024] bf16 ----------------
// EPI 0: scatter qkv -> q,k,v [B,H,T,D] bf16.  EPI 1: fp32 out [M][1024].
template<int EPI>
__global__ __launch_bounds__(256)
void gemm_bt(const short* __restrict__ A, const short* __restrict__ B,
             const float* __restrict__ bias,
             short* __restrict__ oq, short* __restrict__ ok, short* __restrict__ ov,
             float* __restrict__ of) {
  const int K = CDIM;
  int n0 = blockIdx.x * 128, m0 = blockIdx.y * 128;
  int tid = threadIdx.x;
  int lane = tid & 63, w = tid >> 6;
  int wr = w >> 1, wc = w & 1;
  int r16 = lane & 15, g = lane >> 4;

  __shared__ __align__(16) short As[128*32];
  __shared__ __align__(16) short Bs[128*32];

  f32x4 zf = {0.f, 0.f, 0.f, 0.f};
  f32x4 acc[4][4];
  #pragma unroll
  for (int m = 0; m < 4; m++)
    #pragma unroll
    for (int n = 0; n < 4; n++) acc[m][n] = zf;

  int sr = tid >> 2;
  int sc = (tid & 3) * 8;
  const short* ga = A + (long long)(m0 + sr) * K + sc;
  const short* gb = B + (long long)(n0 + sr) * K + sc;
  short* la = As + sr*32 + sc;   // == As + tid*8  (linear, gload-compatible)
  short* lb = Bs + sr*32 + sc;

  for (int k0 = 0; k0 < K; k0 += 32) {
    gload16(ga + k0,           la);
    gload16(ga + k0 + 64*K,    la + 64*32);
    gload16(gb + k0,           lb);
    gload16(gb + k0 + 64*K,    lb + 64*32);
    __syncthreads();
    short8 af[4], bfv[4];
    #pragma unroll
    for (int m = 0; m < 4; m++)
      af[m] = *(const short8*)&As[(wr*64 + m*16 + r16)*32 + g*8];
    #pragma unroll
    for (int n = 0; n < 4; n++)
      bfv[n] = *(const short8*)&Bs[(wc*64 + n*16 + r16)*32 + g*8];
    #pragma unroll
    for (int m = 0; m < 4; m++)
      #pragma unroll
      for (int n = 0; n < 4; n++)
        acc[m][n] = MFMA_B16(af[m], bfv[n], acc[m][n]);
    __syncthreads();
  }

  #pragma unroll
  for (int mi = 0; mi < 4; mi++) {
    #pragma unroll
    for (int n = 0; n < 4; n++) {
      int col = n0 + wc*64 + n*16 + r16;
      float bv = bias[col];
      if constexpr (EPI == 0) {
        int which = col >> 10;
        int c = col & (CDIM-1);
        int hh = c >> 6, dd = c & 63;
        short* outp = (which == 0) ? oq : (which == 1) ? ok : ov;
        #pragma unroll
        for (int j = 0; j < 4; j++) {
          int row = m0 + wr*64 + mi*16 + g*4 + j;
          int b = row >> 11, t = row & (TSEQ-1);
          outp[(((long long)(b*HN + hh))*TSEQ + t)*HD + dd] = bf16_rne(acc[mi][n][j] + bv);
        }
      } else {
        #pragma unroll
        for (int j = 0; j < 4; j++) {
          int row = m0 + wr*64 + mi*16 + g*4 + j;
          of[(long long)row*CDIM + col] = acc[mi][n][j] + bv;
        }
      }
    }
  }
}

// ---------------- V transpose [BH][T][D] -> [BH][D][T] ----------------
__global__ __launch_bounds__(256)
void vtrans_kernel(const short* __restrict__ vin, short* __restrict__ vout) {
  int bh = blockIdx.x >> 5;
  int t0 = (blockIdx.x & 31) * 64;
  __shared__ short tile[64][72];
  int tid = threadIdx.x;
  const short* src = vin + ((long long)bh*TSEQ + t0)*HD;
  #pragma unroll
  for (int i = 0; i < 2; i++) {
    int idx = tid + i*256;
    int r = idx >> 3, c = (idx & 7)*8;
    short8 v = *(const short8*)(src + r*HD + c);
    #pragma unroll
    for (int j = 0; j < 8; j++) tile[r][c+j] = v[j];
  }
  __syncthreads();
  short* dst = vout + (long long)bh*HD*TSEQ + t0;
  #pragma unroll
  for (int i = 0; i < 2; i++) {
    int idx = tid + i*256;
    int d = idx >> 3, c = (idx & 7)*8;
    short8 v;
    #pragma unroll
    for (int j = 0; j < 8; j++) v[j] = tile[c+j][d];
    *(short8*)(dst + (long long)d*TSEQ + c) = v;
  }
}

// ---------------- flash attention with T5 bias, causal ----------------
// grid (T/128, B*H); 4 waves; wave owns 32 q-rows. K/V/P LDS XOR-swizzled (16B units).
__global__ __launch_bounds__(256)
void attn_kernel(const short* __restrict__ Qg, const short* __restrict__ Kg,
                 const short* __restrict__ Vtg, const float* __restrict__ btab,
                 short* __restrict__ outp) {
  int qb = blockIdx.x;
  int bh = blockIdx.y;
  int h = bh & (HN-1), b = bh >> 4;
  int q0 = qb * 128;
  int tid = threadIdx.x, lane = tid & 63, w = tid >> 6;
  int r16 = lane & 15, g = lane >> 4;

  __shared__ __align__(16) short Ks[64*64];   // [kk][d], swizzled
  __shared__ __align__(16) short Vs[64*64];   // [d][kk], swizzled
  __shared__ __align__(16) short Ps[4][32*64];// per-wave P, swizzled
  __shared__ float bias_s[TSEQ];

  for (int i = tid; i < TSEQ; i += 256) bias_s[i] = btab[h*TSEQ + i];

  short8 qa[2][2];
  #pragma unroll
  for (int mi = 0; mi < 2; mi++)
    #pragma unroll
    for (int ks = 0; ks < 2; ks++)
      qa[mi][ks] = *(const short8*)(Qg + ((long long)bh*TSEQ + q0 + w*32 + mi*16 + r16)*HD + ks*32 + g*8);

  f32x4 zf = {0.f,0.f,0.f,0.f};
  f32x4 o[2][4];
  #pragma unroll
  for (int mi = 0; mi < 2; mi++)
    #pragma unroll
    for (int c = 0; c < 4; c++) o[mi][c] = zf;
  float m_[2][4], l_[2][4];
  #pragma unroll
  for (int mi = 0; mi < 2; mi++)
    #pragma unroll
    for (int j = 0; j < 4; j++) { m_[mi][j] = -1e30f; l_[mi][j] = 0.f; }

  int qmax_wave = q0 + w*32 + 31;
  int swz = r16 & 7;

  for (int kb = 0; kb < q0 + 128; kb += 64) {
    // stage K,V with inverse-swizzled global source, linear LDS dest (rule 21)
    #pragma unroll
    for (int i = 0; i < 2; i++) {
      int idx = tid + i*256;
      int r = idx >> 3;
      int cq = ((idx & 7) ^ (r & 7)) * 8;
      gload16(Kg  + ((long long)bh*TSEQ + kb + r)*HD + cq, (short*)Ks + idx*8);
      gload16(Vtg + ((long long)bh*HD  + r)*TSEQ + kb + cq, (short*)Vs + idx*8);
    }
    __syncthreads();
    if (kb <= qmax_wave) {
      // S = Q K^T
      f32x4 s[2][4];
      #pragma unroll
      for (int mi = 0; mi < 2; mi++)
        #pragma unroll
        for (int n = 0; n < 4; n++) s[mi][n] = zf;
      #pragma unroll
      for (int n = 0; n < 4; n++) {
        #pragma unroll
        for (int ks = 0; ks < 2; ks++) {
          short8 kf = *(const short8*)&Ks[(n*16 + r16)*64 + ((ks*4 + g) ^ swz)*8];
          s[0][n] = MFMA_B16(qa[0][ks], kf, s[0][n]);
          s[1][n] = MFMA_B16(qa[1][ks], kf, s[1][n]);
        }
      }
      // scale + bias + causal mask + online softmax; P -> per-wave LDS (bf16)
      #pragma unroll
      for (int mi = 0; mi < 2; mi++) {
        #pragma unroll
        for (int j = 0; j < 4; j++) {
          int q = q0 + w*32 + mi*16 + g*4 + j;
          float rowv[4];
          #pragma unroll
          for (int n = 0; n < 4; n++) {
            int kk = kb + n*16 + r16;
            int d = q - kk;
            rowv[n] = (d >= 0) ? (s[mi][n][j]*0.125f + bias_s[d]) : -1e30f;
          }
          float mx = fmaxf(fmaxf(rowv[0],rowv[1]), fmaxf(rowv[2],rowv[3]));
          mx = fmaxf(mx, __shfl_xor(mx, 1));
          mx = fmaxf(mx, __shfl_xor(mx, 2));
          mx = fmaxf(mx, __shfl_xor(mx, 4));
          mx = fmaxf(mx, __shfl_xor(mx, 8));
          float mnew = fmaxf(m_[mi][j], mx);
          float corr = __expf(m_[mi][j] - mnew);
          float psum = 0.f;
          int qrow = mi*16 + g*4 + j;
          #pragma unroll
          for (int n = 0; n < 4; n++) {
            float p = __expf(rowv[n] - mnew);
            psum += p;
            int kk = n*16 + r16;
            Ps[w][qrow*64 + (((kk >> 3) ^ (qrow & 7))*8) + (kk & 7)] = bf16_rne(p);
          }
          psum += __shfl_xor(psum, 1);
          psum += __shfl_xor(psum, 2);
          psum += __shfl_xor(psum, 4);
          psum += __shfl_xor(psum, 8);
          l_[mi][j] = l_[mi][j]*corr + psum;
          m_[mi][j] = mnew;
          #pragma unroll
          for (int c = 0; c < 4; c++) o[mi][c][j] *= corr;
        }
      }
      // O += P V
      #pragma unroll
      for (int ks = 0; ks < 2; ks++) {
        short8 pf0 = *(const short8*)&Ps[w][(0  + r16)*64 + ((ks*4 + g) ^ swz)*8];
        short8 pf1 = *(const short8*)&Ps[w][(16 + r16)*64 + ((ks*4 + g) ^ swz)*8];
        #pragma unroll
        for (int c = 0; c < 4; c++) {
          short8 vf = *(const short8*)&Vs[(c*16 + r16)*64 + ((ks*4 + g) ^ swz)*8];
          o[0][c] = MFMA_B16(pf0, vf, o[0][c]);
          o[1][c] = MFMA_B16(pf1, vf, o[1][c]);
        }
      }
    }
    __syncthreads();
  }

  #pragma unroll
  for (int mi = 0; mi < 2; mi++) {
    #pragma unroll
    for (int j = 0; j < 4; j++) {
      int t = q0 + w*32 + mi*16 + g*4 + j;
      float inv = 1.0f / l_[mi][j];
      #pragma unroll
      for (int c = 0; c < 4; c++)
        outp[((long long)(b*TSEQ + t))*CDIM + h*HD + c*16 + r16] = bf16_rne(o[mi][c][j] * inv);
    }
  }
}

extern "C" void kernel_launch(void* const* d_in, const int* in_sizes, int n_in,
                              void* d_out, int out_size, void* d_ws, size_t ws_size,
                              hipStream_t stream) {
  (void)in_sizes; (void)n_in; (void)out_size; (void)ws_size;
  const float* x      = (const float*)d_in[0];
  const float* W_attn = (const float*)d_in[1];
  const float* b_attn = (const float*)d_in[2];
  const float* W_proj = (const float*)d_in[3];
  const float* b_proj = (const float*)d_in[4];
  const float* rel    = (const float*)d_in[5];
  float* out = (float*)d_out;
  char* ws = (char*)d_ws;

  short* xb   = (short*)(ws);                  // 16 MB (reused as Vt after QKV GEMM)
  short* wab  = (short*)(ws + 16777216LL);     // 6 MB
  short* wpb  = (short*)(ws + 23068672LL);     // 2 MB
  short* qbuf = (short*)(ws + 25165824LL);     // 16 MB  [B,H,T,D]
  short* kbuf = (short*)(ws + 41943040LL);     // 16 MB  [B,H,T,D]
  short* vbuf = (short*)(ws + 58720256LL);     // 16 MB  [B,H,T,D]
  short* att  = (short*)(ws + 75497472LL);     // 16 MB  [B*T, C]
  float* tab  = (float*)(ws + 92274688LL);     // 128 KB [H][T]
  short* vt   = xb;                            // [B,H,D,T]

  pack_kernel<<<2048, 256, 0, stream>>>(x, W_attn, W_proj, xb, wab, wpb);
  bias_table_kernel<<<8, 256, 0, stream>>>(rel, tab);
  gemm_bt<0><<<dim3(24, 64), 256, 0, stream>>>(xb, wab, b_attn, qbuf, kbuf, vbuf, nullptr);
  vtrans_kernel<<<2048, 256, 0, stream>>>(vbuf, vt);
  attn_kernel<<<dim3(16, 64), 256, 0, stream>>>(qbuf, kbuf, vt, tab, att);
  gemm_bt<1><<<dim3(8, 64), 256, 0, stream>>>(att, wpb, b_proj, nullptr, nullptr, nullptr, out);
}

// Round 2
// 311.437 us; speedup vs baseline: 1.7038x; 1.7038x over previous
//
#include <hip/hip_runtime.h>
#include <hip/hip_bf16.h>

typedef __attribute__((ext_vector_type(8))) short short8;
typedef __attribute__((ext_vector_type(4))) short short4v;
typedef __attribute__((ext_vector_type(4))) float f32x4;

#define DEVI static __device__ __forceinline__

#define MTOK 8192
#define CDIM 1024
#define HN 16
#define HD 64
#define TSEQ 2048

#if defined(__has_builtin)
#if __has_builtin(__builtin_amdgcn_exp2f)
#define EXP2(x) __builtin_amdgcn_exp2f(x)
#else
#define EXP2(x) exp2f(x)
#endif
#else
#define EXP2(x) exp2f(x)
#endif

DEVI short bf16_rne(float f) {
  union { float f; unsigned u; } v; v.f = f;
  unsigned r = v.u + 0x7FFFu + ((v.u >> 16) & 1u);
  return (short)(r >> 16);
}

DEVI void gload16(const void* g, void* l) {
  __builtin_amdgcn_global_load_lds(
      (const __attribute__((address_space(1))) void*)(unsigned long long)g,
      (__attribute__((address_space(3))) void*)(unsigned long long)l, 16, 0, 0);
}

#define MFMA_B16(A,B,C) __builtin_amdgcn_mfma_f32_16x16x32_bf16(A,B,C,0,0,0)

// ---------------- pack: fp32 -> bf16 for x, W_attn, W_proj ----------------
__global__ void pack_kernel(const float* __restrict__ x, const float* __restrict__ Wa,
                            const float* __restrict__ Wp,
                            short* __restrict__ xb, short* __restrict__ wab,
                            short* __restrict__ wpb) {
  const int NX4 = MTOK*CDIM/4, NA4 = 3*CDIM*CDIM/4, NP4 = CDIM*CDIM/4;
  const int total = NX4 + NA4 + NP4;
  for (int i = blockIdx.x*blockDim.x + threadIdx.x; i < total; i += gridDim.x*blockDim.x) {
    const float* src; short* dst; int off;
    if (i < NX4)          { src = x;  dst = xb;  off = i*4; }
    else if (i < NX4+NA4) { src = Wa; dst = wab; off = (i-NX4)*4; }
    else                  { src = Wp; dst = wpb; off = (i-NX4-NA4)*4; }
    float4 v = *(const float4*)(src + off);
    short4v r;
    r.x = bf16_rne(v.x); r.y = bf16_rne(v.y); r.z = bf16_rne(v.z); r.w = bf16_rne(v.w);
    *(short4v*)(dst + off) = r;
  }
}

// ---------------- T5 relative-position bias table: tab[h][dist] ----------------
__global__ void bias_table_kernel(const float* __restrict__ rel_emb, float* __restrict__ tab) {
  int d = blockIdx.x*blockDim.x + threadIdx.x;
  if (d >= TSEQ) return;
  int bucket;
  if (d < 16) bucket = d;
  else {
    int bl = 16 + (int)(logf((float)d / 16.0f + 1e-10f) / 2.0794415416798357f * 16.0f);
    bucket = bl < 31 ? bl : 31;
  }
  for (int h = 0; h < HN; h++) tab[h*TSEQ + d] = rel_emb[bucket*HN + h];
}

// ---------------- GEMM C = A @ B^T (+bias), A[M][1024], B[N][1024] bf16 ----------------
template<int EPI>
__global__ __launch_bounds__(256)
void gemm_bt(const short* __restrict__ A, const short* __restrict__ B,
             const float* __restrict__ bias,
             short* __restrict__ oq, short* __restrict__ ok, short* __restrict__ ov,
             float* __restrict__ of) {
  const int K = CDIM;
  // bijective XCD swizzle on linearized block id (nwg % 8 == 0 for both grids)
  int nbx = gridDim.x;
  int idx = blockIdx.y * nbx + blockIdx.x;
  int cpx = (nbx * gridDim.y) >> 3;
  int sw = (idx & 7) * cpx + (idx >> 3);
  int n0 = (sw % nbx) * 128, m0 = (sw / nbx) * 128;

  int tid = threadIdx.x;
  int lane = tid & 63, w = tid >> 6;
  int wr = w >> 1, wc = w & 1;
  int r16 = lane & 15, g = lane >> 4;

  __shared__ __align__(16) short As[128*32];
  __shared__ __align__(16) short Bs[128*32];

  f32x4 zf = {0.f, 0.f, 0.f, 0.f};
  f32x4 acc[4][4];
  #pragma unroll
  for (int m = 0; m < 4; m++)
    #pragma unroll
    for (int n = 0; n < 4; n++) acc[m][n] = zf;

  int sr = tid >> 2;
  int sc = (tid & 3) * 8;
  const short* ga = A + (long long)(m0 + sr) * K + sc;
  const short* gb = B + (long long)(n0 + sr) * K + sc;
  short* la = As + sr*32 + sc;
  short* lb = Bs + sr*32 + sc;

  for (int k0 = 0; k0 < K; k0 += 32) {
    gload16(ga + k0,           la);
    gload16(ga + k0 + 64*K,    la + 64*32);
    gload16(gb + k0,           lb);
    gload16(gb + k0 + 64*K,    lb + 64*32);
    __syncthreads();
    short8 af[4], bfv[4];
    #pragma unroll
    for (int m = 0; m < 4; m++)
      af[m] = *(const short8*)&As[(wr*64 + m*16 + r16)*32 + g*8];
    #pragma unroll
    for (int n = 0; n < 4; n++)
      bfv[n] = *(const short8*)&Bs[(wc*64 + n*16 + r16)*32 + g*8];
    #pragma unroll
    for (int m = 0; m < 4; m++)
      #pragma unroll
      for (int n = 0; n < 4; n++)
        acc[m][n] = MFMA_B16(af[m], bfv[n], acc[m][n]);
    __syncthreads();
  }

  #pragma unroll
  for (int mi = 0; mi < 4; mi++) {
    #pragma unroll
    for (int n = 0; n < 4; n++) {
      int col = n0 + wc*64 + n*16 + r16;
      float bv = bias[col];
      if constexpr (EPI == 0) {
        int which = col >> 10;
        int c = col & (CDIM-1);
        int hh = c >> 6, dd = c & 63;
        short* outp = (which == 0) ? oq : (which == 1) ? ok : ov;
        #pragma unroll
        for (int j = 0; j < 4; j++) {
          int row = m0 + wr*64 + mi*16 + g*4 + j;
          int b = row >> 11, t = row & (TSEQ-1);
          outp[(((long long)(b*HN + hh))*TSEQ + t)*HD + dd] = bf16_rne(acc[mi][n][j] + bv);
        }
      } else {
        #pragma unroll
        for (int j = 0; j < 4; j++) {
          int row = m0 + wr*64 + mi*16 + g*4 + j;
          of[(long long)row*CDIM + col] = acc[mi][n][j] + bv;
        }
      }
    }
  }
}

// ---------------- V transpose [BH][T][D] -> [BH][D][T] ----------------
__global__ __launch_bounds__(256)
void vtrans_kernel(const short* __restrict__ vin, short* __restrict__ vout) {
  int bh = blockIdx.x >> 5;
  int t0 = (blockIdx.x & 31) * 64;
  __shared__ short tile[64][72];
  int tid = threadIdx.x;
  const short* src = vin + ((long long)bh*TSEQ + t0)*HD;
  #pragma unroll
  for (int i = 0; i < 2; i++) {
    int idx = tid + i*256;
    int r = idx >> 3, c = (idx & 7)*8;
    short8 v = *(const short8*)(src + r*HD + c);
    #pragma unroll
    for (int j = 0; j < 8; j++) tile[r][c+j] = v[j];
  }
  __syncthreads();
  short* dst = vout + (long long)bh*HD*TSEQ + t0;
  #pragma unroll
  for (int i = 0; i < 2; i++) {
    int idx = tid + i*256;
    int d = idx >> 3, c = (idx & 7)*8;
    short8 v;
    #pragma unroll
    for (int j = 0; j < 8; j++) v[j] = tile[c+j][d];
    *(short8*)(dst + (long long)d*TSEQ + c) = v;
  }
}

// ---------------- flash attention, swapped-operand softmax ----------------
// grid (bh=64, 16); qb = 15 - blockIdx.y (LPT). 4 waves, wave owns 32 q-rows.
// S^T = mfma(K,Q): acc col = q (lane-local per r16) -> in-register row softmax,
// only 2 shfl_xor per row. O^T = mfma(V,P): q stays lane-local for rescale.
__global__ __launch_bounds__(256)
void attn_kernel(const short* __restrict__ Qg, const short* __restrict__ Kg,
                 const short* __restrict__ Vtg, const float* __restrict__ btab,
                 short* __restrict__ outp) {
  int bh = blockIdx.x;
  int qb = 15 - (int)blockIdx.y;
  int h = bh & (HN-1), b = bh >> 4;
  int q0 = qb * 128;
  int tid = threadIdx.x, lane = tid & 63, w = tid >> 6;
  int r16 = lane & 15, g = lane >> 4;

  __shared__ __align__(16) short Ks[64*64];   // [kk][d], 16B-unit XOR swizzled
  __shared__ __align__(16) short Vs[64*64];   // [d][kk], swizzled
  __shared__ __align__(16) short Ps[8][1024]; // [w*2+mi][q16][k64], swizzled
  __shared__ float bias_s[TSEQ];              // bias * log2e

  for (int i = tid; i < TSEQ; i += 256) bias_s[i] = btab[h*TSEQ + i] * 1.44269504f;

  short8 qa[2][2];
  #pragma unroll
  for (int mi = 0; mi < 2; mi++)
    #pragma unroll
    for (int ks = 0; ks < 2; ks++)
      qa[mi][ks] = *(const short8*)(Qg + ((long long)bh*TSEQ + q0 + w*32 + mi*16 + r16)*HD + ks*32 + g*8);

  f32x4 zf = {0.f,0.f,0.f,0.f};
  f32x4 o[2][4];
  #pragma unroll
  for (int mi = 0; mi < 2; mi++)
    #pragma unroll
    for (int c = 0; c < 4; c++) o[mi][c] = zf;
  float m_[2] = {-1e30f, -1e30f}, l_[2] = {0.f, 0.f};

  int qmax_wave = q0 + w*32 + 31;
  int swz = r16 & 7;
  int qrel = q0 + w*32 + r16;          // lane's q = qrel + mi*16
  const float SC = 0.18033688f;        // 0.125 * log2(e)

  for (int kb = 0; kb < q0 + 128; kb += 64) {
    #pragma unroll
    for (int i = 0; i < 2; i++) {
      int idx = tid + i*256;
      int r = idx >> 3;
      int cq = ((idx & 7) ^ (r & 7)) * 8;
      gload16(Kg  + ((long long)bh*TSEQ + kb + r)*HD + cq, (short*)Ks + idx*8);
      gload16(Vtg + ((long long)bh*HD  + r)*TSEQ + kb + cq, (short*)Vs + idx*8);
    }
    __syncthreads();
    if (kb <= qmax_wave) {
      f32x4 s[2][4];
      #pragma unroll
      for (int mi = 0; mi < 2; mi++)
        #pragma unroll
        for (int n = 0; n < 4; n++) s[mi][n] = zf;
      #pragma unroll
      for (int n = 0; n < 4; n++) {
        #pragma unroll
        for (int ks = 0; ks < 2; ks++) {
          short8 kf = *(const short8*)&Ks[(n*16 + r16)*64 + ((ks*4 + g) ^ swz)*8];
          s[0][n] = MFMA_B16(kf, qa[0][ks], s[0][n]);
          s[1][n] = MFMA_B16(kf, qa[1][ks], s[1][n]);
        }
      }
      #pragma unroll
      for (int mi = 0; mi < 2; mi++) {
        int dbase = qrel + mi*16 - kb - g*4;   // d = dbase - n*16 - j
        float rowv[4][4];
        #pragma unroll
        for (int n = 0; n < 4; n++)
          #pragma unroll
          for (int j = 0; j < 4; j++) {
            int d = dbase - n*16 - j;
            rowv[n][j] = (d >= 0) ? s[mi][n][j]*SC + bias_s[d] : -1e30f;
          }
        float mx = rowv[0][0];
        #pragma unroll
        for (int n = 0; n < 4; n++)
          #pragma unroll
          for (int j = 0; j < 4; j++) mx = fmaxf(mx, rowv[n][j]);
        mx = fmaxf(mx, __shfl_xor(mx, 16));
        mx = fmaxf(mx, __shfl_xor(mx, 32));
        float mnew = fmaxf(m_[mi], mx);
        float corr = EXP2(m_[mi] - mnew);
        m_[mi] = mnew;
        float ps_ = 0.f;
        unsigned pk[4][2];
        #pragma unroll
        for (int n = 0; n < 4; n++) {
          #pragma unroll
          for (int jj = 0; jj < 2; jj++) {
            float p0 = EXP2(rowv[n][jj*2]   - mnew);
            float p1 = EXP2(rowv[n][jj*2+1] - mnew);
            ps_ += p0 + p1;
            pk[n][jj] = ((unsigned)(unsigned short)bf16_rne(p1) << 16) |
                        (unsigned)(unsigned short)bf16_rne(p0);
          }
        }
        ps_ += __shfl_xor(ps_, 16);
        ps_ += __shfl_xor(ps_, 32);
        l_[mi] = l_[mi]*corr + ps_;
        #pragma unroll
        for (int c = 0; c < 4; c++) o[mi][c] *= corr;
        // P write: row q=r16, k = n*16 + g*4 + {0..3}; 16B-unit XOR swizzle
        char* prow = (char*)Ps[w*2 + mi] + r16*128 + ((g & 1) << 3);
        #pragma unroll
        for (int n = 0; n < 4; n++)
          *(uint2*)(prow + ((((n*2 + (g >> 1)) ^ swz)) << 4)) = make_uint2(pk[n][0], pk[n][1]);
      }
      // O^T += V^T P^T : mfma(A=V rows d, B=P rows q)
      #pragma unroll
      for (int ks = 0; ks < 2; ks++) {
        short8 pf0 = *(const short8*)((char*)Ps[w*2+0] + r16*128 + (((ks*4 + g) ^ swz) << 4));
        short8 pf1 = *(const short8*)((char*)Ps[w*2+1] + r16*128 + (((ks*4 + g) ^ swz) << 4));
        #pragma unroll
        for (int c = 0; c < 4; c++) {
          short8 vf = *(const short8*)&Vs[(c*16 + r16)*64 + ((ks*4 + g) ^ swz)*8];
          o[0][c] = MFMA_B16(vf, pf0, o[0][c]);
          o[1][c] = MFMA_B16(vf, pf1, o[1][c]);
        }
      }
    }
    __syncthreads();
  }

  // epilogue: lane's q = qrel + mi*16; d = c*16 + g*4 + j; paired u32 stores
  #pragma unroll
  for (int mi = 0; mi < 2; mi++) {
    float inv = 1.0f / l_[mi];
    long long base = ((long long)(b*TSEQ + qrel + mi*16))*CDIM + h*HD;
    #pragma unroll
    for (int c = 0; c < 4; c++) {
      #pragma unroll
      for (int jj = 0; jj < 2; jj++) {
        unsigned pv = ((unsigned)(unsigned short)bf16_rne(o[mi][c][jj*2+1]*inv) << 16) |
                      (unsigned)(unsigned short)bf16_rne(o[mi][c][jj*2]*inv);
        *(unsigned*)(outp + base + c*16 + g*4 + jj*2) = pv;
      }
    }
  }
}

extern "C" void kernel_launch(void* const* d_in, const int* in_sizes, int n_in,
                              void* d_out, int out_size, void* d_ws, size_t ws_size,
                              hipStream_t stream) {
  (void)in_sizes; (void)n_in; (void)out_size; (void)ws_size;
  const float* x      = (const float*)d_in[0];
  const float* W_attn = (const float*)d_in[1];
  const float* b_attn = (const float*)d_in[2];
  const float* W_proj = (const float*)d_in[3];
  const float* b_proj = (const float*)d_in[4];
  const float* rel    = (const float*)d_in[5];
  float* out = (float*)d_out;
  char* ws = (char*)d_ws;

  short* xb   = (short*)(ws);                  // 16 MB (reused as Vt after QKV GEMM)
  short* wab  = (short*)(ws + 16777216LL);     // 6 MB
  short* wpb  = (short*)(ws + 23068672LL);     // 2 MB
  short* qbuf = (short*)(ws + 25165824LL);     // 16 MB  [B,H,T,D]
  short* kbuf = (short*)(ws + 41943040LL);     // 16 MB  [B,H,T,D]
  short* vbuf = (short*)(ws + 58720256LL);     // 16 MB  [B,H,T,D]
  short* att  = (short*)(ws + 75497472LL);     // 16 MB  [B*T, C]
  float* tab  = (float*)(ws + 92274688LL);     // 128 KB [H][T]
  short* vt   = xb;                            // [B,H,D,T]

  pack_kernel<<<2048, 256, 0, stream>>>(x, W_attn, W_proj, xb, wab, wpb);
  bias_table_kernel<<<8, 256, 0, stream>>>(rel, tab);
  gemm_bt<0><<<dim3(24, 64), 256, 0, stream>>>(xb, wab, b_attn, qbuf, kbuf, vbuf, nullptr);
  vtrans_kernel<<<2048, 256, 0, stream>>>(vbuf, vt);
  attn_kernel<<<dim3(64, 16), 256, 0, stream>>>(qbuf, kbuf, vt, tab, att);
  gemm_bt<1><<<dim3(8, 64), 256, 0, stream>>>(att, wpb, b_proj, nullptr, nullptr, nullptr, out);
}

// Round 3
// 273.837 us; speedup vs baseline: 1.9377x; 1.1373x over previous
//
#include <hip/hip_runtime.h>
#include <hip/hip_bf16.h>

typedef __attribute__((ext_vector_type(8))) short short8;
typedef __attribute__((ext_vector_type(4))) short short4v;
typedef __attribute__((ext_vector_type(4))) float f32x4;

#define DEVI static __device__ __forceinline__

#define MTOK 8192
#define CDIM 1024
#define HN 16
#define HD 64
#define TSEQ 2048

#if defined(__has_builtin)
#if __has_builtin(__builtin_amdgcn_exp2f)
#define EXP2(x) __builtin_amdgcn_exp2f(x)
#else
#define EXP2(x) exp2f(x)
#endif
#else
#define EXP2(x) exp2f(x)
#endif

DEVI short bf16_rne(float f) {
  union { float f; unsigned u; } v; v.f = f;
  unsigned r = v.u + 0x7FFFu + ((v.u >> 16) & 1u);
  return (short)(r >> 16);
}

DEVI unsigned cvt_pk_bf16(float lo, float hi) {
  unsigned r;
  asm("v_cvt_pk_bf16_f32 %0, %1, %2" : "=v"(r) : "v"(lo), "v"(hi));
  return r;
}

DEVI void gload16(const void* g, void* l) {
  __builtin_amdgcn_global_load_lds(
      (const __attribute__((address_space(1))) void*)(unsigned long long)g,
      (__attribute__((address_space(3))) void*)(unsigned long long)l, 16, 0, 0);
}

#define MFMA_B16(A,B,C) __builtin_amdgcn_mfma_f32_16x16x32_bf16(A,B,C,0,0,0)

// ---------------- pack: fp32 -> bf16 for x, W_attn, W_proj ----------------
__global__ void pack_kernel(const float* __restrict__ x, const float* __restrict__ Wa,
                            const float* __restrict__ Wp,
                            short* __restrict__ xb, short* __restrict__ wab,
                            short* __restrict__ wpb) {
  const int NX4 = MTOK*CDIM/4, NA4 = 3*CDIM*CDIM/4, NP4 = CDIM*CDIM/4;
  const int total = NX4 + NA4 + NP4;
  for (int i = blockIdx.x*blockDim.x + threadIdx.x; i < total; i += gridDim.x*blockDim.x) {
    const float* src; short* dst; int off;
    if (i < NX4)          { src = x;  dst = xb;  off = i*4; }
    else if (i < NX4+NA4) { src = Wa; dst = wab; off = (i-NX4)*4; }
    else                  { src = Wp; dst = wpb; off = (i-NX4-NA4)*4; }
    float4 v = *(const float4*)(src + off);
    short4v r;
    r.x = bf16_rne(v.x); r.y = bf16_rne(v.y); r.z = bf16_rne(v.z); r.w = bf16_rne(v.w);
    *(short4v*)(dst + off) = r;
  }
}

// ---------------- T5 relative-position bias table: tab[h][dist] ----------------
__global__ void bias_table_kernel(const float* __restrict__ rel_emb, float* __restrict__ tab) {
  int d = blockIdx.x*blockDim.x + threadIdx.x;
  if (d >= TSEQ) return;
  int bucket;
  if (d < 16) bucket = d;
  else {
    int bl = 16 + (int)(logf((float)d / 16.0f + 1e-10f) / 2.0794415416798357f * 16.0f);
    bucket = bl < 31 ? bl : 31;
  }
  for (int h = 0; h < HN; h++) tab[h*TSEQ + d] = rel_emb[bucket*HN + h];
}

// ---------------- GEMM C = A @ B^T (+bias), A[M][1024], B[N][1024] bf16 ----------------
template<int EPI>
__global__ __launch_bounds__(256)
void gemm_bt(const short* __restrict__ A, const short* __restrict__ B,
             const float* __restrict__ bias,
             short* __restrict__ oq, short* __restrict__ ok, short* __restrict__ ov,
             float* __restrict__ of) {
  const int K = CDIM;
  int nbx = gridDim.x;
  int idx = blockIdx.y * nbx + blockIdx.x;
  int cpx = (nbx * gridDim.y) >> 3;
  int sw = (idx & 7) * cpx + (idx >> 3);
  int n0 = (sw % nbx) * 128, m0 = (sw / nbx) * 128;

  int tid = threadIdx.x;
  int lane = tid & 63, w = tid >> 6;
  int wr = w >> 1, wc = w & 1;
  int r16 = lane & 15, g = lane >> 4;

  __shared__ __align__(16) short As[128*32];
  __shared__ __align__(16) short Bs[128*32];

  f32x4 zf = {0.f, 0.f, 0.f, 0.f};
  f32x4 acc[4][4];
  #pragma unroll
  for (int m = 0; m < 4; m++)
    #pragma unroll
    for (int n = 0; n < 4; n++) acc[m][n] = zf;

  int sr = tid >> 2;
  int sc = (tid & 3) * 8;
  const short* ga = A + (long long)(m0 + sr) * K + sc;
  const short* gb = B + (long long)(n0 + sr) * K + sc;
  short* la = As + sr*32 + sc;
  short* lb = Bs + sr*32 + sc;

  for (int k0 = 0; k0 < K; k0 += 32) {
    gload16(ga + k0,           la);
    gload16(ga + k0 + 64*K,    la + 64*32);
    gload16(gb + k0,           lb);
    gload16(gb + k0 + 64*K,    lb + 64*32);
    __syncthreads();
    short8 af[4], bfv[4];
    #pragma unroll
    for (int m = 0; m < 4; m++)
      af[m] = *(const short8*)&As[(wr*64 + m*16 + r16)*32 + g*8];
    #pragma unroll
    for (int n = 0; n < 4; n++)
      bfv[n] = *(const short8*)&Bs[(wc*64 + n*16 + r16)*32 + g*8];
    #pragma unroll
    for (int m = 0; m < 4; m++)
      #pragma unroll
      for (int n = 0; n < 4; n++)
        acc[m][n] = MFMA_B16(af[m], bfv[n], acc[m][n]);
    __syncthreads();
  }

  #pragma unroll
  for (int mi = 0; mi < 4; mi++) {
    #pragma unroll
    for (int n = 0; n < 4; n++) {
      int col = n0 + wc*64 + n*16 + r16;
      float bv = bias[col];
      if constexpr (EPI == 0) {
        int which = col >> 10;
        int c = col & (CDIM-1);
        int hh = c >> 6, dd = c & 63;
        short* outp = (which == 0) ? oq : (which == 1) ? ok : ov;
        #pragma unroll
        for (int j = 0; j < 4; j++) {
          int row = m0 + wr*64 + mi*16 + g*4 + j;
          int b = row >> 11, t = row & (TSEQ-1);
          outp[(((long long)(b*HN + hh))*TSEQ + t)*HD + dd] = bf16_rne(acc[mi][n][j] + bv);
        }
      } else {
        #pragma unroll
        for (int j = 0; j < 4; j++) {
          int row = m0 + wr*64 + mi*16 + g*4 + j;
          of[(long long)row*CDIM + col] = acc[mi][n][j] + bv;
        }
      }
    }
  }
}

// ---------------- V transpose [BH][T][D] -> [BH][D][T] ----------------
__global__ __launch_bounds__(256)
void vtrans_kernel(const short* __restrict__ vin, short* __restrict__ vout) {
  int bh = blockIdx.x >> 5;
  int t0 = (blockIdx.x & 31) * 64;
  __shared__ short tile[64][66];   // pad 66: writes 2-way, transpose reads 4-way
  int tid = threadIdx.x;
  const short* src = vin + ((long long)bh*TSEQ + t0)*HD;
  #pragma unroll
  for (int i = 0; i < 2; i++) {
    int idx = tid + i*256;
    int r = idx >> 3, c = (idx & 7)*8;
    short8 v = *(const short8*)(src + r*HD + c);
    #pragma unroll
    for (int j = 0; j < 8; j++) tile[r][c+j] = v[j];
  }
  __syncthreads();
  short* dst = vout + (long long)bh*HD*TSEQ + t0;
  #pragma unroll
  for (int i = 0; i < 2; i++) {
    int idx = tid + i*256;
    int d = idx >> 3, c = (idx & 7)*8;
    short8 v;
    #pragma unroll
    for (int j = 0; j < 8; j++) v[j] = tile[c+j][d];
    *(short8*)(dst + (long long)d*TSEQ + c) = v;
  }
}

// ---------------- flash attention, swapped-operand softmax ----------------
// S^T = mfma(K,Q): q lane-local. Far tiles (d>=113): bucket saturates -> bias
// is a per-head constant: no gather, no causal select. Defer-max rescale (T13),
// psum via ones-MFMA, cvt_pk bf16 packing.
__global__ __launch_bounds__(256)
void attn_kernel(const short* __restrict__ Qg, const short* __restrict__ Kg,
                 const short* __restrict__ Vtg, const float* __restrict__ btab,
                 short* __restrict__ outp) {
  int bh = blockIdx.x;
  int qb = 15 - (int)blockIdx.y;
  int h = bh & (HN-1), b = bh >> 4;
  int q0 = qb * 128;
  int tid = threadIdx.x, lane = tid & 63, w = tid >> 6;
  int r16 = lane & 15, g = lane >> 4;

  __shared__ __align__(16) short Ks[64*64];   // [kk][d], 16B-unit XOR swizzled
  __shared__ __align__(16) short Vs[64*64];   // [d][kk], swizzled
  __shared__ __align__(16) short Ps[8][1024]; // [w*2+mi][q16][k64], swizzled
  __shared__ float bias_s[256];               // bias*log2e, d in [0,256)

  bias_s[tid & 255] = btab[h*TSEQ + (tid & 255)] * 1.44269504f;
  float cb = btab[h*TSEQ + 255] * 1.44269504f;   // saturated-bucket constant

  short8 qa[2][2];
  #pragma unroll
  for (int mi = 0; mi < 2; mi++)
    #pragma unroll
    for (int ks = 0; ks < 2; ks++)
      qa[mi][ks] = *(const short8*)(Qg + ((long long)bh*TSEQ + q0 + w*32 + mi*16 + r16)*HD + ks*32 + g*8);

  f32x4 zf = {0.f,0.f,0.f,0.f};
  f32x4 o[2][4];
  #pragma unroll
  for (int mi = 0; mi < 2; mi++)
    #pragma unroll
    for (int c = 0; c < 4; c++) o[mi][c] = zf;
  float m_[2] = {-1e30f, -1e30f}, l_[2] = {0.f, 0.f};

  const short8 ones = {0x3f80,0x3f80,0x3f80,0x3f80,0x3f80,0x3f80,0x3f80,0x3f80};
  int qmax_wave = q0 + w*32 + 31;
  int swz = r16 & 7;
  int qrel = q0 + w*32 + r16;
  const float SC = 0.18033688f;        // 0.125 * log2(e)

  for (int kb = 0; kb < q0 + 128; kb += 64) {
    #pragma unroll
    for (int i = 0; i < 2; i++) {
      int idx = tid + i*256;
      int r = idx >> 3;
      int cq = ((idx & 7) ^ (r & 7)) * 8;
      gload16(Kg  + ((long long)bh*TSEQ + kb + r)*HD + cq, (short*)Ks + idx*8);
      gload16(Vtg + ((long long)bh*HD  + r)*TSEQ + kb + cq, (short*)Vs + idx*8);
    }
    __syncthreads();
    if (kb <= qmax_wave) {
      f32x4 s[2][4];
      #pragma unroll
      for (int mi = 0; mi < 2; mi++)
        #pragma unroll
        for (int n = 0; n < 4; n++) s[mi][n] = zf;
      #pragma unroll
      for (int n = 0; n < 4; n++) {
        #pragma unroll
        for (int ks = 0; ks < 2; ks++) {
          short8 kf = *(const short8*)&Ks[(n*16 + r16)*64 + ((ks*4 + g) ^ swz)*8];
          s[0][n] = MFMA_B16(kf, qa[0][ks], s[0][n]);
          s[1][n] = MFMA_B16(kf, qa[1][ks], s[1][n]);
        }
      }
      bool far = (kb + 176 <= q0 + w*32);   // whole tile at saturated bucket, no mask
      #pragma unroll
      for (int mi = 0; mi < 2; mi++) {
        char* prow = (char*)Ps[w*2 + mi] + r16*128 + ((g & 1) << 3);
        if (far) {
          float smax = s[mi][0][0];
          #pragma unroll
          for (int n = 0; n < 4; n++)
            #pragma unroll
            for (int j = 0; j < 4; j++) smax = fmaxf(smax, s[mi][n][j]);
          float mx = smax*SC + cb;
          mx = fmaxf(mx, __shfl_xor(mx, 16));
          mx = fmaxf(mx, __shfl_xor(mx, 32));
          float mnew;
          if (__all(mx <= m_[mi] + 8.0f)) {
            mnew = m_[mi];                      // defer: skip rescale
          } else {
            mnew = fmaxf(m_[mi], mx);
            float corr = EXP2(m_[mi] - mnew);
            l_[mi] *= corr;
            #pragma unroll
            for (int c = 0; c < 4; c++) o[mi][c] *= corr;
            m_[mi] = mnew;
          }
          float cc = cb - mnew;
          #pragma unroll
          for (int n = 0; n < 4; n++) {
            unsigned u0 = cvt_pk_bf16(EXP2(__builtin_fmaf(s[mi][n][0], SC, cc)),
                                      EXP2(__builtin_fmaf(s[mi][n][1], SC, cc)));
            unsigned u1 = cvt_pk_bf16(EXP2(__builtin_fmaf(s[mi][n][2], SC, cc)),
                                      EXP2(__builtin_fmaf(s[mi][n][3], SC, cc)));
            *(uint2*)(prow + ((((n*2 + (g >> 1)) ^ swz)) << 4)) = make_uint2(u0, u1);
          }
        } else {
          int dbase = qrel + mi*16 - kb - g*4;
          float rowv[4][4];
          #pragma unroll
          for (int n = 0; n < 4; n++)
            #pragma unroll
            for (int j = 0; j < 4; j++) {
              int d = dbase - n*16 - j;
              rowv[n][j] = (d >= 0) ? s[mi][n][j]*SC + bias_s[d] : -1e30f;
            }
          float mx = rowv[0][0];
          #pragma unroll
          for (int n = 0; n < 4; n++)
            #pragma unroll
            for (int j = 0; j < 4; j++) mx = fmaxf(mx, rowv[n][j]);
          mx = fmaxf(mx, __shfl_xor(mx, 16));
          mx = fmaxf(mx, __shfl_xor(mx, 32));
          float mnew;
          if (__all(mx <= m_[mi] + 8.0f)) {
            mnew = m_[mi];
          } else {
            mnew = fmaxf(m_[mi], mx);
            float corr = EXP2(m_[mi] - mnew);
            l_[mi] *= corr;
            #pragma unroll
            for (int c = 0; c < 4; c++) o[mi][c] *= corr;
            m_[mi] = mnew;
          }
          #pragma unroll
          for (int n = 0; n < 4; n++) {
            unsigned u0 = cvt_pk_bf16(EXP2(rowv[n][0] - mnew), EXP2(rowv[n][1] - mnew));
            unsigned u1 = cvt_pk_bf16(EXP2(rowv[n][2] - mnew), EXP2(rowv[n][3] - mnew));
            *(uint2*)(prow + ((((n*2 + (g >> 1)) ^ swz)) << 4)) = make_uint2(u0, u1);
          }
        }
      }
      // O^T += V^T P^T ; l += colsum(P) via ones-MFMA
      f32x4 lacc[2] = {zf, zf};
      #pragma unroll
      for (int ks = 0; ks < 2; ks++) {
        short8 pf0 = *(const short8*)((char*)Ps[w*2+0] + r16*128 + (((ks*4 + g) ^ swz) << 4));
        short8 pf1 = *(const short8*)((char*)Ps[w*2+1] + r16*128 + (((ks*4 + g) ^ swz) << 4));
        lacc[0] = MFMA_B16(ones, pf0, lacc[0]);
        lacc[1] = MFMA_B16(ones, pf1, lacc[1]);
        #pragma unroll
        for (int c = 0; c < 4; c++) {
          short8 vf = *(const short8*)&Vs[(c*16 + r16)*64 + ((ks*4 + g) ^ swz)*8];
          o[0][c] = MFMA_B16(vf, pf0, o[0][c]);
          o[1][c] = MFMA_B16(vf, pf1, o[1][c]);
        }
      }
      l_[0] += lacc[0][0];
      l_[1] += lacc[1][0];
    }
    __syncthreads();
  }

  #pragma unroll
  for (int mi = 0; mi < 2; mi++) {
    float inv = 1.0f / l_[mi];
    long long base = ((long long)(b*TSEQ + qrel + mi*16))*CDIM + h*HD;
    #pragma unroll
    for (int c = 0; c < 4; c++) {
      #pragma unroll
      for (int jj = 0; jj < 2; jj++) {
        unsigned pv = cvt_pk_bf16(o[mi][c][jj*2]*inv, o[mi][c][jj*2+1]*inv);
        *(unsigned*)(outp + base + c*16 + g*4 + jj*2) = pv;
      }
    }
  }
}

extern "C" void kernel_launch(void* const* d_in, const int* in_sizes, int n_in,
                              void* d_out, int out_size, void* d_ws, size_t ws_size,
                              hipStream_t stream) {
  (void)in_sizes; (void)n_in; (void)out_size; (void)ws_size;
  const float* x      = (const float*)d_in[0];
  const float* W_attn = (const float*)d_in[1];
  const float* b_attn = (const float*)d_in[2];
  const float* W_proj = (const float*)d_in[3];
  const float* b_proj = (const float*)d_in[4];
  const float* rel    = (const float*)d_in[5];
  float* out = (float*)d_out;
  char* ws = (char*)d_ws;

  short* xb   = (short*)(ws);                  // 16 MB (reused as Vt after QKV GEMM)
  short* wab  = (short*)(ws + 16777216LL);     // 6 MB
  short* wpb  = (short*)(ws + 23068672LL);     // 2 MB
  short* qbuf = (short*)(ws + 25165824LL);     // 16 MB  [B,H,T,D]
  short* kbuf = (short*)(ws + 41943040LL);     // 16 MB  [B,H,T,D]
  short* vbuf = (short*)(ws + 58720256LL);     // 16 MB  [B,H,T,D]
  short* att  = (short*)(ws + 75497472LL);     // 16 MB  [B*T, C]
  float* tab  = (float*)(ws + 92274688LL);     // 128 KB [H][T]
  short* vt   = xb;                            // [B,H,D,T]

  pack_kernel<<<2048, 256, 0, stream>>>(x, W_attn, W_proj, xb, wab, wpb);
  bias_table_kernel<<<8, 256, 0, stream>>>(rel, tab);
  gemm_bt<0><<<dim3(24, 64), 256, 0, stream>>>(xb, wab, b_attn, qbuf, kbuf, vbuf, nullptr);
  vtrans_kernel<<<2048, 256, 0, stream>>>(vbuf, vt);
  attn_kernel<<<dim3(64, 16), 256, 0, stream>>>(qbuf, kbuf, vt, tab, att);
  gemm_bt<1><<<dim3(8, 64), 256, 0, stream>>>(att, wpb, b_proj, nullptr, nullptr, nullptr, out);
}

// Round 4
// 249.655 us; speedup vs baseline: 2.1254x; 1.0969x over previous
//
#include <hip/hip_runtime.h>
#include <hip/hip_bf16.h>

typedef __attribute__((ext_vector_type(8))) short short8;
typedef __attribute__((ext_vector_type(4))) short short4v;
typedef __attribute__((ext_vector_type(4))) float f32x4;

#define DEVI static __device__ __forceinline__

#define MTOK 8192
#define CDIM 1024
#define HN 16
#define HD 64
#define TSEQ 2048

#if defined(__has_builtin)
#if __has_builtin(__builtin_amdgcn_exp2f)
#define EXP2(x) __builtin_amdgcn_exp2f(x)
#else
#define EXP2(x) exp2f(x)
#endif
#else
#define EXP2(x) exp2f(x)
#endif

DEVI short bf16_rne(float f) {
  union { float f; unsigned u; } v; v.f = f;
  unsigned r = v.u + 0x7FFFu + ((v.u >> 16) & 1u);
  return (short)(r >> 16);
}

DEVI unsigned cvt_pk_bf16(float lo, float hi) {
  unsigned r;
  asm("v_cvt_pk_bf16_f32 %0, %1, %2" : "=v"(r) : "v"(lo), "v"(hi));
  return r;
}

DEVI void gload16(const void* g, void* l) {
  __builtin_amdgcn_global_load_lds(
      (const __attribute__((address_space(1))) void*)(unsigned long long)g,
      (__attribute__((address_space(3))) void*)(unsigned long long)l, 16, 0, 0);
}

#define MFMA_B16(A,B,C) __builtin_amdgcn_mfma_f32_16x16x32_bf16(A,B,C,0,0,0)

// ---------------- pack: fp32 -> bf16 for x, W_attn, W_proj ----------------
__global__ void pack_kernel(const float* __restrict__ x, const float* __restrict__ Wa,
                            const float* __restrict__ Wp,
                            short* __restrict__ xb, short* __restrict__ wab,
                            short* __restrict__ wpb) {
  const int NX4 = MTOK*CDIM/4, NA4 = 3*CDIM*CDIM/4, NP4 = CDIM*CDIM/4;
  const int total = NX4 + NA4 + NP4;
  for (int i = blockIdx.x*blockDim.x + threadIdx.x; i < total; i += gridDim.x*blockDim.x) {
    const float* src; short* dst; int off;
    if (i < NX4)          { src = x;  dst = xb;  off = i*4; }
    else if (i < NX4+NA4) { src = Wa; dst = wab; off = (i-NX4)*4; }
    else                  { src = Wp; dst = wpb; off = (i-NX4-NA4)*4; }
    float4 v = *(const float4*)(src + off);
    short4v r;
    r.x = bf16_rne(v.x); r.y = bf16_rne(v.y); r.z = bf16_rne(v.z); r.w = bf16_rne(v.w);
    *(short4v*)(dst + off) = r;
  }
}

// ---------------- T5 relative-position bias table: tab[h][dist] ----------------
__global__ void bias_table_kernel(const float* __restrict__ rel_emb, float* __restrict__ tab) {
  int d = blockIdx.x*blockDim.x + threadIdx.x;
  if (d >= TSEQ) return;
  int bucket;
  if (d < 16) bucket = d;
  else {
    int bl = 16 + (int)(logf((float)d / 16.0f + 1e-10f) / 2.0794415416798357f * 16.0f);
    bucket = bl < 31 ? bl : 31;
  }
  for (int h = 0; h < HN; h++) tab[h*TSEQ + d] = rel_emb[bucket*HN + h];
}

// ------- pipelined GEMM C = A @ B^T (+bias): tile 256x128, BK=32, 3 LDS bufs,
// prefetch distance 2, counted vmcnt (T4), 16B-unit XOR swizzle (T2), setprio (T5),
// XCD-bijective block swizzle (T1). 8 waves as 4M x 2N, per-wave 64x64.
// EPI 0: QKV scatter (q,k row-major [bh][t][d]; v written TRANSPOSED [bh][d][t]).
// EPI 1: fp32 out [M][1024].
template<int EPI>
__global__ __launch_bounds__(512)
void gemm2(const short* __restrict__ A, const short* __restrict__ B,
           const float* __restrict__ bias,
           short* __restrict__ oq, short* __restrict__ ok, short* __restrict__ vt,
           float* __restrict__ of) {
  const int K = CDIM;
  int nbx = gridDim.x;
  int idx = blockIdx.y * nbx + blockIdx.x;
  int cpx = (nbx * gridDim.y) >> 3;
  int sw = (idx & 7) * cpx + (idx >> 3);
  int n0 = (sw % nbx) * 128, m0 = (sw / nbx) * 256;

  int tid = threadIdx.x, lane = tid & 63, w = tid >> 6;
  int wm = w >> 1, wn = w & 1;
  int r16 = lane & 15, g = lane >> 4;

  __shared__ __align__(16) short As[3][256*32];   // 48 KB
  __shared__ __align__(16) short Bs[3][128*32];   // 24 KB

  f32x4 zf = {0.f,0.f,0.f,0.f};
  f32x4 acc[4][4];
  #pragma unroll
  for (int mf = 0; mf < 4; mf++)
    #pragma unroll
    for (int nf = 0; nf < 4; nf++) acc[mf][nf] = zf;

  // staging map: LDS slot s = (row r = s>>2, 16B-unit u = s&3), linear dest;
  // global source pre-swizzled: fetch unit u ^ ((r>>1)&3)  (both-sides rule)
  int r0 = tid >> 2;
  int cswz = (((tid & 3) ^ ((r0 >> 1) & 3)) << 3);
  long long aofs = (long long)(m0 + r0) * K + cswz;
  long long bofs = (long long)(n0 + r0) * K + cswz;

  auto STAGE = [&](int kt, int bi) {
    gload16(A + aofs + kt*32,          (short*)As[bi] + tid*8);
    gload16(A + aofs + kt*32 + 128*K,  (short*)As[bi] + 4096 + tid*8);
    gload16(B + bofs + kt*32,          (short*)Bs[bi] + tid*8);
  };

  STAGE(0, 0); STAGE(1, 1);
  asm volatile("s_waitcnt vmcnt(3)" ::: "memory");   // tile0 landed, tile1 in flight
  __builtin_amdgcn_s_barrier();
  __builtin_amdgcn_sched_barrier(0);

  int swz3 = (r16 >> 1) & 3;
  int fbA = (wm*64 + r16)*32 + ((g ^ swz3) << 3);
  int fbB = (wn*64 + r16)*32 + ((g ^ swz3) << 3);

  for (int kt = 0; kt < 32; kt++) {
    int cur = kt % 3;
    if (kt < 30) STAGE(kt + 2, (kt + 2) % 3);   // buffer freed at end of iter kt-1
    const short* Ab = As[cur];
    const short* Bb = Bs[cur];
    short8 af[4], bf[4];
    #pragma unroll
    for (int mf = 0; mf < 4; mf++) af[mf] = *(const short8*)(Ab + fbA + mf*512);
    #pragma unroll
    for (int nf = 0; nf < 4; nf++) bf[nf] = *(const short8*)(Bb + fbB + nf*512);
    __builtin_amdgcn_s_setprio(1);
    #pragma unroll
    for (int mf = 0; mf < 4; mf++)
      #pragma unroll
      for (int nf = 0; nf < 4; nf++)
        acc[mf][nf] = MFMA_B16(af[mf], bf[nf], acc[mf][nf]);
    __builtin_amdgcn_s_setprio(0);
    if (kt < 30) asm volatile("s_waitcnt vmcnt(3)" ::: "memory");  // tile kt+1 landed
    else         asm volatile("s_waitcnt vmcnt(0)" ::: "memory");  // tail drain
    __builtin_amdgcn_s_barrier();
    __builtin_amdgcn_sched_barrier(0);
  }

  int b = m0 >> 11;                      // 256 | 2048: block within one batch
  int mrel = (m0 & 2047) + wm*64 + g*4;  // + mf*16 + j
  if constexpr (EPI == 0) {
    int which = n0 >> 10;                // block-uniform: q/k/v
    int hh = ((n0 & 1023) >> 6) + wn;
    long long bh = (long long)(b*HN + hh);
    #pragma unroll
    for (int nf = 0; nf < 4; nf++) {
      int dd = nf*16 + r16;
      float bv = bias[n0 + wn*64 + dd];
      if (which == 2) {                  // V: transposed store [bh][d][t], 8B packed
        short* vdst = vt + (bh*HD + dd)*TSEQ + mrel;
        #pragma unroll
        for (int mf = 0; mf < 4; mf++) {
          short4v pv;
          #pragma unroll
          for (int j = 0; j < 4; j++) pv[j] = bf16_rne(acc[mf][nf][j] + bv);
          *(short4v*)(vdst + mf*16) = pv;
        }
      } else {                           // Q/K: row-major [bh][t][d]
        short* odst = (which == 0 ? oq : ok) + bh*TSEQ*HD + dd;
        #pragma unroll
        for (int mf = 0; mf < 4; mf++)
          #pragma unroll
          for (int j = 0; j < 4; j++)
            odst[(long long)(mrel + mf*16 + j)*HD] = bf16_rne(acc[mf][nf][j] + bv);
      }
    }
  } else {
    #pragma unroll
    for (int nf = 0; nf < 4; nf++) {
      int col = n0 + wn*64 + nf*16 + r16;
      float bv = bias[col];
      #pragma unroll
      for (int mf = 0; mf < 4; mf++)
        #pragma unroll
        for (int j = 0; j < 4; j++)
          of[(long long)(m0 + wm*64 + mf*16 + g*4 + j)*CDIM + col] = acc[mf][nf][j] + bv;
    }
  }
}

// ---------------- flash attention, swapped-operand softmax ----------------
__global__ __launch_bounds__(256)
void attn_kernel(const short* __restrict__ Qg, const short* __restrict__ Kg,
                 const short* __restrict__ Vtg, const float* __restrict__ btab,
                 short* __restrict__ outp) {
  int bh = blockIdx.x;
  int qb = 15 - (int)blockIdx.y;
  int h = bh & (HN-1), b = bh >> 4;
  int q0 = qb * 128;
  int tid = threadIdx.x, lane = tid & 63, w = tid >> 6;
  int r16 = lane & 15, g = lane >> 4;

  __shared__ __align__(16) short Ks[64*64];   // [kk][d], 16B-unit XOR swizzled
  __shared__ __align__(16) short Vs[64*64];   // [d][kk], swizzled
  __shared__ __align__(16) short Ps[8][1024]; // [w*2+mi][q16][k64], swizzled
  __shared__ float bias_s[256];               // bias*log2e, d in [0,256)

  bias_s[tid & 255] = btab[h*TSEQ + (tid & 255)] * 1.44269504f;
  float cb = btab[h*TSEQ + 255] * 1.44269504f;   // saturated-bucket constant

  short8 qa[2][2];
  #pragma unroll
  for (int mi = 0; mi < 2; mi++)
    #pragma unroll
    for (int ks = 0; ks < 2; ks++)
      qa[mi][ks] = *(const short8*)(Qg + ((long long)bh*TSEQ + q0 + w*32 + mi*16 + r16)*HD + ks*32 + g*8);

  f32x4 zf = {0.f,0.f,0.f,0.f};
  f32x4 o[2][4];
  #pragma unroll
  for (int mi = 0; mi < 2; mi++)
    #pragma unroll
    for (int c = 0; c < 4; c++) o[mi][c] = zf;
  float m_[2] = {-1e30f, -1e30f}, l_[2] = {0.f, 0.f};

  const short8 ones = {0x3f80,0x3f80,0x3f80,0x3f80,0x3f80,0x3f80,0x3f80,0x3f80};
  int qmax_wave = q0 + w*32 + 31;
  int swz = r16 & 7;
  int qrel = q0 + w*32 + r16;
  const float SC = 0.18033688f;        // 0.125 * log2(e)

  for (int kb = 0; kb < q0 + 128; kb += 64) {
    #pragma unroll
    for (int i = 0; i < 2; i++) {
      int idx = tid + i*256;
      int r = idx >> 3;
      int cq = ((idx & 7) ^ (r & 7)) * 8;
      gload16(Kg  + ((long long)bh*TSEQ + kb + r)*HD + cq, (short*)Ks + idx*8);
      gload16(Vtg + ((long long)bh*HD  + r)*TSEQ + kb + cq, (short*)Vs + idx*8);
    }
    __syncthreads();
    if (kb <= qmax_wave) {
      f32x4 s[2][4];
      #pragma unroll
      for (int mi = 0; mi < 2; mi++)
        #pragma unroll
        for (int n = 0; n < 4; n++) s[mi][n] = zf;
      #pragma unroll
      for (int n = 0; n < 4; n++) {
        #pragma unroll
        for (int ks = 0; ks < 2; ks++) {
          short8 kf = *(const short8*)&Ks[(n*16 + r16)*64 + ((ks*4 + g) ^ swz)*8];
          s[0][n] = MFMA_B16(kf, qa[0][ks], s[0][n]);
          s[1][n] = MFMA_B16(kf, qa[1][ks], s[1][n]);
        }
      }
      bool far = (kb + 176 <= q0 + w*32);   // whole tile at saturated bucket, no mask
      #pragma unroll
      for (int mi = 0; mi < 2; mi++) {
        char* prow = (char*)Ps[w*2 + mi] + r16*128 + ((g & 1) << 3);
        if (far) {
          float smax = s[mi][0][0];
          #pragma unroll
          for (int n = 0; n < 4; n++)
            #pragma unroll
            for (int j = 0; j < 4; j++) smax = fmaxf(smax, s[mi][n][j]);
          float mx = smax*SC + cb;
          mx = fmaxf(mx, __shfl_xor(mx, 16));
          mx = fmaxf(mx, __shfl_xor(mx, 32));
          float mnew;
          if (__all(mx <= m_[mi] + 8.0f)) {
            mnew = m_[mi];                      // defer: skip rescale
          } else {
            mnew = fmaxf(m_[mi], mx);
            float corr = EXP2(m_[mi] - mnew);
            l_[mi] *= corr;
            #pragma unroll
            for (int c = 0; c < 4; c++) o[mi][c] *= corr;
            m_[mi] = mnew;
          }
          float cc = cb - mnew;
          #pragma unroll
          for (int n = 0; n < 4; n++) {
            unsigned u0 = cvt_pk_bf16(EXP2(__builtin_fmaf(s[mi][n][0], SC, cc)),
                                      EXP2(__builtin_fmaf(s[mi][n][1], SC, cc)));
            unsigned u1 = cvt_pk_bf16(EXP2(__builtin_fmaf(s[mi][n][2], SC, cc)),
                                      EXP2(__builtin_fmaf(s[mi][n][3], SC, cc)));
            *(uint2*)(prow + ((((n*2 + (g >> 1)) ^ swz)) << 4)) = make_uint2(u0, u1);
          }
        } else {
          int dbase = qrel + mi*16 - kb - g*4;
          float rowv[4][4];
          #pragma unroll
          for (int n = 0; n < 4; n++)
            #pragma unroll
            for (int j = 0; j < 4; j++) {
              int d = dbase - n*16 - j;
              rowv[n][j] = (d >= 0) ? s[mi][n][j]*SC + bias_s[d] : -1e30f;
            }
          float mx = rowv[0][0];
          #pragma unroll
          for (int n = 0; n < 4; n++)
            #pragma unroll
            for (int j = 0; j < 4; j++) mx = fmaxf(mx, rowv[n][j]);
          mx = fmaxf(mx, __shfl_xor(mx, 16));
          mx = fmaxf(mx, __shfl_xor(mx, 32));
          float mnew;
          if (__all(mx <= m_[mi] + 8.0f)) {
            mnew = m_[mi];
          } else {
            mnew = fmaxf(m_[mi], mx);
            float corr = EXP2(m_[mi] - mnew);
            l_[mi] *= corr;
            #pragma unroll
            for (int c = 0; c < 4; c++) o[mi][c] *= corr;
            m_[mi] = mnew;
          }
          #pragma unroll
          for (int n = 0; n < 4; n++) {
            unsigned u0 = cvt_pk_bf16(EXP2(rowv[n][0] - mnew), EXP2(rowv[n][1] - mnew));
            unsigned u1 = cvt_pk_bf16(EXP2(rowv[n][2] - mnew), EXP2(rowv[n][3] - mnew));
            *(uint2*)(prow + ((((n*2 + (g >> 1)) ^ swz)) << 4)) = make_uint2(u0, u1);
          }
        }
      }
      // O^T += V^T P^T ; l += colsum(P) via ones-MFMA
      f32x4 lacc[2] = {zf, zf};
      #pragma unroll
      for (int ks = 0; ks < 2; ks++) {
        short8 pf0 = *(const short8*)((char*)Ps[w*2+0] + r16*128 + (((ks*4 + g) ^ swz) << 4));
        short8 pf1 = *(const short8*)((char*)Ps[w*2+1] + r16*128 + (((ks*4 + g) ^ swz) << 4));
        lacc[0] = MFMA_B16(ones, pf0, lacc[0]);
        lacc[1] = MFMA_B16(ones, pf1, lacc[1]);
        #pragma unroll
        for (int c = 0; c < 4; c++) {
          short8 vf = *(const short8*)&Vs[(c*16 + r16)*64 + ((ks*4 + g) ^ swz)*8];
          o[0][c] = MFMA_B16(vf, pf0, o[0][c]);
          o[1][c] = MFMA_B16(vf, pf1, o[1][c]);
        }
      }
      l_[0] += lacc[0][0];
      l_[1] += lacc[1][0];
    }
    __syncthreads();
  }

  #pragma unroll
  for (int mi = 0; mi < 2; mi++) {
    float inv = 1.0f / l_[mi];
    long long base = ((long long)(b*TSEQ + qrel + mi*16))*CDIM + h*HD;
    #pragma unroll
    for (int c = 0; c < 4; c++) {
      #pragma unroll
      for (int jj = 0; jj < 2; jj++) {
        unsigned pv = cvt_pk_bf16(o[mi][c][jj*2]*inv, o[mi][c][jj*2+1]*inv);
        *(unsigned*)(outp + base + c*16 + g*4 + jj*2) = pv;
      }
    }
  }
}

extern "C" void kernel_launch(void* const* d_in, const int* in_sizes, int n_in,
                              void* d_out, int out_size, void* d_ws, size_t ws_size,
                              hipStream_t stream) {
  (void)in_sizes; (void)n_in; (void)out_size; (void)ws_size;
  const float* x      = (const float*)d_in[0];
  const float* W_attn = (const float*)d_in[1];
  const float* b_attn = (const float*)d_in[2];
  const float* W_proj = (const float*)d_in[3];
  const float* b_proj = (const float*)d_in[4];
  const float* rel    = (const float*)d_in[5];
  float* out = (float*)d_out;
  char* ws = (char*)d_ws;

  short* xb   = (short*)(ws);                  // 16 MB
  short* wab  = (short*)(ws + 16777216LL);     // 6 MB
  short* wpb  = (short*)(ws + 23068672LL);     // 2 MB
  short* qbuf = (short*)(ws + 25165824LL);     // 16 MB  [B,H,T,D]
  short* kbuf = (short*)(ws + 41943040LL);     // 16 MB  [B,H,T,D]
  short* vt   = (short*)(ws + 58720256LL);     // 16 MB  [B,H,D,T] (written by gemm2<0>)
  short* att  = (short*)(ws + 75497472LL);     // 16 MB  [B*T, C]
  float* tab  = (float*)(ws + 92274688LL);     // 128 KB [H][T]

  pack_kernel<<<2048, 256, 0, stream>>>(x, W_attn, W_proj, xb, wab, wpb);
  bias_table_kernel<<<8, 256, 0, stream>>>(rel, tab);
  gemm2<0><<<dim3(24, 32), 512, 0, stream>>>(xb, wab, b_attn, qbuf, kbuf, vt, nullptr);
  attn_kernel<<<dim3(64, 16), 256, 0, stream>>>(qbuf, kbuf, vt, tab, att);
  gemm2<1><<<dim3(8, 32), 512, 0, stream>>>(att, wpb, b_proj, nullptr, nullptr, nullptr, out);
}